// Round 2
// baseline (3866.788 us; speedup 1.0000x reference)
//
#include <hip/hip_runtime.h>
#include <hip/hip_bf16.h>

#define NNODE 8192
#define DEG   32
#define DIN   256
#define EDIM  64
#define KC    576            // 2*DIN + EDIM
#define DD    512            // internal width D
#define NH    8
#define HC    64             // head dim C
#define CP    32             // D/(H*2)
#define MEDGE (NNODE*DEG)

typedef __attribute__((ext_vector_type(8))) short short8;
typedef __attribute__((ext_vector_type(4))) short short4v;
typedef __attribute__((ext_vector_type(4))) float floatx4;

__device__ __forceinline__ ushort f2bf(float f) {
  union { float f; unsigned int i; } v; v.f = f;
  return (ushort)((v.i + 0x7fffu + ((v.i >> 16) & 1u)) >> 16);
}
__device__ __forceinline__ float gelu_f(float z) {
  return 0.5f * z * (1.0f + erff(z * 0.70710678118654752f));
}
__device__ __forceinline__ floatx4 zero4() { floatx4 v = {0.f, 0.f, 0.f, 0.f}; return v; }

// load 8 consecutive fp32 and convert to a bf16 MFMA half-fragment
__device__ __forceinline__ short8 ld_cvt8(const float* __restrict__ p) {
  floatx4 a = *(const floatx4*)(p);
  floatx4 b = *(const floatx4*)(p + 4);
  short8 r;
  r[0] = (short)f2bf(a[0]); r[1] = (short)f2bf(a[1]);
  r[2] = (short)f2bf(a[2]); r[3] = (short)f2bf(a[3]);
  r[4] = (short)f2bf(b[0]); r[5] = (short)f2bf(b[1]);
  r[6] = (short)f2bf(b[2]); r[7] = (short)f2bf(b[3]);
  return r;
}

#define MFMA16(a, b, c) __builtin_amdgcn_mfma_f32_16x16x32_bf16((a), (b), (c), 0, 0, 0)

// LDS row pads: rows 16B-aligned (pad multiple of 8 bf16)
#define EXP 520   // 512 + 8
#define QP  72    // 64 + 8
#define VP  40    // 32 + 8

// ws layout (bf16 elements)
#define WS_WC 0
#define WS_WI (WS_WC + 512*KC)          // 294912
#define WS_WO (WS_WI + 1536*DD)         // +786432
#define WS_END (WS_WO + 512*DD)         // +262144

__global__ __launch_bounds__(256, 2) void nt_fused(
    const float* __restrict__ x,  const float* __restrict__ ea,
    const int*   __restrict__ e,
    const ushort* __restrict__ Wc, const float* __restrict__ bc,
    const ushort* __restrict__ Wi, const float* __restrict__ bi,
    const ushort* __restrict__ Wo, const float* __restrict__ bo,
    float* __restrict__ out)
{
  __shared__ ushort sEX[DEG * EXP];   // ex  [32][512]  (bf16)
  __shared__ ushort sAO[DEG * EXP];   // attn out [32][512]
  __shared__ ushort sQ [DEG * QP];    // q [32][64]; P overlays with stride VP
  __shared__ ushort sK [DEG * QP];    // k [32][64]
  __shared__ ushort sVT[HC  * VP];    // v^T [64][32]

  const int node = blockIdx.x;
  const int m0   = node * DEG;
  const int tid  = threadIdx.x;
  const int w    = tid >> 6;    // wave 0..3
  const int l    = tid & 63;
  const int lr   = l & 15;      // A-row / B-col / D-col lane index
  const int lg   = l >> 4;      // k-group / row-group

  const int src = e[m0];                       // same source for whole group
  const int dA0 = e[MEDGE + m0 + lr];          // dst for A rows (M-tile 0)
  const int dA1 = e[MEDGE + m0 + 16 + lr];     // dst for A rows (M-tile 1)

  // ================= GEMM1: ex = gelu(gelu(feat @ Wc^T + bc)) =================
  floatx4 acc0[8], acc1[8];
  #pragma unroll
  for (int nt = 0; nt < 8; ++nt) { acc0[nt] = zero4(); acc1[nt] = zero4(); }

  const float* xsrc = x + (size_t)src * DIN;
  // k-steps 0..7 : A rows are all x[src] -> identical for both M-tiles
  #pragma unroll
  for (int s = 0; s < 8; ++s) {
    short8 af = ld_cvt8(xsrc + s * 32 + lg * 8);
    #pragma unroll
    for (int nt = 0; nt < 8; ++nt) {
      const int col = w * 128 + nt * 16 + lr;
      short8 bf = *(const short8*)(Wc + (size_t)col * KC + s * 32 + lg * 8);
      acc0[nt] = MFMA16(af, bf, acc0[nt]);
    }
  }
  #pragma unroll
  for (int nt = 0; nt < 8; ++nt) acc1[nt] = acc0[nt];

  // k-steps 8..15 : x[dst]
  const float* xd0 = x + (size_t)dA0 * DIN;
  const float* xd1 = x + (size_t)dA1 * DIN;
  #pragma unroll
  for (int s = 0; s < 8; ++s) {
    short8 a0 = ld_cvt8(xd0 + s * 32 + lg * 8);
    short8 a1 = ld_cvt8(xd1 + s * 32 + lg * 8);
    #pragma unroll
    for (int nt = 0; nt < 8; ++nt) {
      const int col = w * 128 + nt * 16 + lr;
      short8 bf = *(const short8*)(Wc + (size_t)col * KC + 256 + s * 32 + lg * 8);
      acc0[nt] = MFMA16(a0, bf, acc0[nt]);
      acc1[nt] = MFMA16(a1, bf, acc1[nt]);
    }
  }
  // k-steps 16..17 : edge_attr
  const float* ea0 = ea + (size_t)(m0 + lr) * EDIM;
  const float* ea1 = ea + (size_t)(m0 + 16 + lr) * EDIM;
  #pragma unroll
  for (int s = 0; s < 2; ++s) {
    short8 a0 = ld_cvt8(ea0 + s * 32 + lg * 8);
    short8 a1 = ld_cvt8(ea1 + s * 32 + lg * 8);
    #pragma unroll
    for (int nt = 0; nt < 8; ++nt) {
      const int col = w * 128 + nt * 16 + lr;
      short8 bf = *(const short8*)(Wc + (size_t)col * KC + 512 + s * 32 + lg * 8);
      acc0[nt] = MFMA16(a0, bf, acc0[nt]);
      acc1[nt] = MFMA16(a1, bf, acc1[nt]);
    }
  }
  // epilogue: bias + gelu(gelu()) -> sEX
  #pragma unroll
  for (int nt = 0; nt < 8; ++nt) {
    const int col = w * 128 + nt * 16 + lr;
    const float bias = bc[col];
    #pragma unroll
    for (int i = 0; i < 4; ++i) {
      sEX[(lg * 4 + i) * EXP + col]      = f2bf(gelu_f(gelu_f(acc0[nt][i] + bias)));
      sEX[(16 + lg * 4 + i) * EXP + col] = f2bf(gelu_f(gelu_f(acc1[nt][i] + bias)));
    }
  }
  __syncthreads();

  // ================= per-head: QKV -> softmax(QK^T/8) -> PV =================
  #pragma unroll 1
  for (int h = 0; h < NH; ++h) {
    // QKV: wave w computes flat 16-col tiles 3w..3w+2 of [q0..3,k0..3,v0..3]
    floatx4 qacc[2][3];
    #pragma unroll
    for (int mt = 0; mt < 2; ++mt)
      #pragma unroll
      for (int t = 0; t < 3; ++t) qacc[mt][t] = zero4();
    int trow[3];
    #pragma unroll
    for (int t = 0; t < 3; ++t) {
      const int ft = 3 * w + t;
      trow[t] = (ft >> 2) * DD + h * HC + (ft & 3) * 16 + lr;
    }
    #pragma unroll
    for (int s = 0; s < 16; ++s) {
      short8 a0 = *(const short8*)(&sEX[lr * EXP + s * 32 + lg * 8]);
      short8 a1 = *(const short8*)(&sEX[(16 + lr) * EXP + s * 32 + lg * 8]);
      #pragma unroll
      for (int t = 0; t < 3; ++t) {
        short8 bf = *(const short8*)(Wi + (size_t)trow[t] * DD + s * 32 + lg * 8);
        qacc[0][t] = MFMA16(a0, bf, qacc[0][t]);
        qacc[1][t] = MFMA16(a1, bf, qacc[1][t]);
      }
    }
    #pragma unroll
    for (int t = 0; t < 3; ++t) {
      const int ft = 3 * w + t;
      const int seg = ft >> 2, st = ft & 3;
      const float bias = bi[trow[t]];
      #pragma unroll
      for (int mt = 0; mt < 2; ++mt) {
        if (seg == 2) {                       // v: store transposed VT[vcol][krow]
          short4v pk;
          #pragma unroll
          for (int i = 0; i < 4; ++i) pk[i] = (short)f2bf(qacc[mt][t][i] + bias);
          *(short4v*)(&sVT[(st * 16 + lr) * VP + mt * 16 + lg * 4]) = pk;
        } else {
          ushort* dstp = (seg == 0) ? sQ : sK;
          #pragma unroll
          for (int i = 0; i < 4; ++i)
            dstp[(mt * 16 + lg * 4 + i) * QP + st * 16 + lr] = f2bf(qacc[mt][t][i] + bias);
        }
      }
    }
    __syncthreads();

    // scores + row softmax into registers (waves 0,1)
    float pr0[4], pr1[4];
    if (w < 2) {
      const int mt = w;
      floatx4 sc0 = zero4(), sc1 = zero4();
      #pragma unroll
      for (int s = 0; s < 2; ++s) {
        short8 af = *(const short8*)(&sQ[(mt * 16 + lr) * QP + s * 32 + lg * 8]);
        short8 b0 = *(const short8*)(&sK[lr * QP + s * 32 + lg * 8]);
        short8 b1 = *(const short8*)(&sK[(16 + lr) * QP + s * 32 + lg * 8]);
        sc0 = MFMA16(af, b0, sc0);
        sc1 = MFMA16(af, b1, sc1);
      }
      #pragma unroll
      for (int i = 0; i < 4; ++i) {
        float v0 = sc0[i] * 0.125f, v1 = sc1[i] * 0.125f;
        float mx = fmaxf(v0, v1);
        #pragma unroll
        for (int d2 = 1; d2 < 16; d2 <<= 1) mx = fmaxf(mx, __shfl_xor(mx, d2));
        float e0 = expf(v0 - mx), e1 = expf(v1 - mx);
        float sm = e0 + e1;
        #pragma unroll
        for (int d2 = 1; d2 < 16; d2 <<= 1) sm += __shfl_xor(sm, d2);
        const float inv = 1.0f / sm;
        pr0[i] = e0 * inv;
        pr1[i] = e1 * inv;
      }
    }
    __syncthreads();   // all q/k reads done before P overlays sQ

    if (w < 2) {
      const int mt = w;
      #pragma unroll
      for (int i = 0; i < 4; ++i) {
        sQ[(mt * 16 + lg * 4 + i) * VP + lr]      = f2bf(pr0[i]);
        sQ[(mt * 16 + lg * 4 + i) * VP + 16 + lr] = f2bf(pr1[i]);
      }
    }
    __syncthreads();

    // PV: o = P @ v ; wave w -> M-tile w&1, v-col tiles (w>>1)*2 + {0,1}
    {
      const int mt = w & 1;
      const int ntb = (w >> 1) * 2;
      short8 af = *(const short8*)(&sQ[(mt * 16 + lr) * VP + lg * 8]);
      short8 b0 = *(const short8*)(&sVT[(ntb * 16 + lr) * VP + lg * 8]);
      short8 b1 = *(const short8*)(&sVT[((ntb + 1) * 16 + lr) * VP + lg * 8]);
      floatx4 o0 = MFMA16(af, b0, zero4());
      floatx4 o1 = MFMA16(af, b1, zero4());
      #pragma unroll
      for (int i = 0; i < 4; ++i) {
        sAO[(mt * 16 + lg * 4 + i) * EXP + h * HC + ntb * 16 + lr]       = f2bf(o0[i]);
        sAO[(mt * 16 + lg * 4 + i) * EXP + h * HC + (ntb + 1) * 16 + lr] = f2bf(o1[i]);
      }
    }
    __syncthreads();
  }

  // ================= GEMM3: h = gelu(AO @ Wo^T + bo) + weighted-mean agg =====
  floatx4 h3[2][8];
  #pragma unroll
  for (int mt = 0; mt < 2; ++mt)
    #pragma unroll
    for (int nt = 0; nt < 8; ++nt) h3[mt][nt] = zero4();
  #pragma unroll
  for (int s = 0; s < 16; ++s) {
    short8 a0 = *(const short8*)(&sAO[lr * EXP + s * 32 + lg * 8]);
    short8 a1 = *(const short8*)(&sAO[(16 + lr) * EXP + s * 32 + lg * 8]);
    #pragma unroll
    for (int nt = 0; nt < 8; ++nt) {
      const int col = w * 128 + nt * 16 + lr;
      short8 bf = *(const short8*)(Wo + (size_t)col * DD + s * 32 + lg * 8);
      h3[0][nt] = MFMA16(a0, bf, h3[0][nt]);
      h3[1][nt] = MFMA16(a1, bf, h3[1][nt]);
    }
  }
  #pragma unroll
  for (int nt = 0; nt < 8; ++nt) {
    const float bias = bo[w * 128 + nt * 16 + lr];
    #pragma unroll
    for (int i = 0; i < 4; ++i) {
      h3[0][nt][i] = gelu_f(h3[0][nt][i] + bias);
      h3[1][nt][i] = gelu_f(h3[1][nt][i] + bias);
    }
  }
  // logits = mean over ch1 (tiles 2,3 -> head 2w ; tiles 6,7 -> head 2w+1)
  float lgA[2][4], lgB[2][4];
  #pragma unroll
  for (int mt = 0; mt < 2; ++mt)
    #pragma unroll
    for (int i = 0; i < 4; ++i) {
      float tA = h3[mt][2][i] + h3[mt][3][i];
      float tB = h3[mt][6][i] + h3[mt][7][i];
      #pragma unroll
      for (int d2 = 1; d2 < 16; d2 <<= 1) { tA += __shfl_xor(tA, d2); tB += __shfl_xor(tB, d2); }
      lgA[mt][i] = tA * (1.0f / 32.0f);
      lgB[mt][i] = tB * (1.0f / 32.0f);
    }
  // alpha = softmax over the 32 edges of the group, per head
  float mxA = -1e30f, mxB = -1e30f;
  #pragma unroll
  for (int mt = 0; mt < 2; ++mt)
    #pragma unroll
    for (int i = 0; i < 4; ++i) { mxA = fmaxf(mxA, lgA[mt][i]); mxB = fmaxf(mxB, lgB[mt][i]); }
  mxA = fmaxf(mxA, __shfl_xor(mxA, 16)); mxA = fmaxf(mxA, __shfl_xor(mxA, 32));
  mxB = fmaxf(mxB, __shfl_xor(mxB, 16)); mxB = fmaxf(mxB, __shfl_xor(mxB, 32));
  float eAv[2][4], eBv[2][4];
  float sA = 0.f, sB = 0.f;
  #pragma unroll
  for (int mt = 0; mt < 2; ++mt)
    #pragma unroll
    for (int i = 0; i < 4; ++i) {
      eAv[mt][i] = expf(lgA[mt][i] - mxA); sA += eAv[mt][i];
      eBv[mt][i] = expf(lgB[mt][i] - mxB); sB += eBv[mt][i];
    }
  sA += __shfl_xor(sA, 16); sA += __shfl_xor(sA, 32);
  sB += __shfl_xor(sB, 16); sB += __shfl_xor(sB, 32);
  const float iA = 1.0f / sA, iB = 1.0f / sB;

  // wz scatter: out[dst][head*32 + p] += h_ch0 * alpha
  #pragma unroll
  for (int mt = 0; mt < 2; ++mt)
    #pragma unroll
    for (int i = 0; i < 4; ++i) {
      const int r  = mt * 16 + lg * 4 + i;
      const int d1 = e[MEDGE + m0 + r];
      float* bp = out + (size_t)d1 * 256;
      const float aA = eAv[mt][i] * iA;
      const float aB = eBv[mt][i] * iB;
      atomicAdd(bp + (2 * w) * CP + lr,          h3[mt][0][i] * aA);
      atomicAdd(bp + (2 * w) * CP + 16 + lr,     h3[mt][1][i] * aA);
      atomicAdd(bp + (2 * w + 1) * CP + lr,      h3[mt][4][i] * aB);
      atomicAdd(bp + (2 * w + 1) * CP + 16 + lr, h3[mt][5][i] * aB);
    }
}

// fp32 -> bf16 weight pre-convert (4 elems/thread)
__global__ __launch_bounds__(256) void cvt_w(const float* __restrict__ src,
                                             ushort* __restrict__ dst, int n4)
{
  const int i = blockIdx.x * 256 + threadIdx.x;
  if (i < n4) {
    floatx4 v = *(const floatx4*)(src + (size_t)i * 4);
    short4v r;
    #pragma unroll
    for (int j = 0; j < 4; ++j) r[j] = (short)f2bf(v[j]);
    *(short4v*)(dst + (size_t)i * 4) = r;
  }
}

extern "C" void kernel_launch(void* const* d_in, const int* in_sizes, int n_in,
                              void* d_out, int out_size, void* d_ws, size_t ws_size,
                              hipStream_t stream)
{
  (void)in_sizes; (void)n_in; (void)ws_size;
  const float* x  = (const float*)d_in[0];
  const float* ea = (const float*)d_in[1];
  const int*   e  = (const int*)d_in[2];
  const float* Wc = (const float*)d_in[3];
  const float* bc = (const float*)d_in[4];
  const float* Wi = (const float*)d_in[5];
  const float* bi = (const float*)d_in[6];
  const float* Wo = (const float*)d_in[7];
  const float* bo = (const float*)d_in[8];

  ushort* wsb = (ushort*)d_ws;
  ushort* Wcb = wsb + WS_WC;
  ushort* Wib = wsb + WS_WI;
  ushort* Wob = wsb + WS_WO;

  cvt_w<<<dim3((512 * KC / 4 + 255) / 256), dim3(256), 0, stream>>>(Wc, Wcb, 512 * KC / 4);
  cvt_w<<<dim3((1536 * DD / 4 + 255) / 256), dim3(256), 0, stream>>>(Wi, Wib, 1536 * DD / 4);
  cvt_w<<<dim3((512 * DD / 4 + 255) / 256), dim3(256), 0, stream>>>(Wo, Wob, 512 * DD / 4);

  float* out = (float*)d_out;
  hipMemsetAsync(out, 0, (size_t)out_size * sizeof(float), stream);

  nt_fused<<<dim3(NNODE), dim3(256), 0, stream>>>(x, ea, e, Wcb, bc, Wib, bi, Wob, bo, out);
}